// Round 3
// baseline (37511.200 us; speedup 1.0000x reference)
//
#include <hip/hip_runtime.h>
#include <math.h>

// ---------------------------------------------------------------------------
// FISTA sparse solver, L=128, D=512, M=2048, MAX_ITER=200, EPS=1e-5.
// R3: 3 launches total. Persistent kernels with hand-rolled grid barrier
// (generation-based, device-scope atomics + __threadfence) eliminate ~600
// graph-node dispatches (~10-20us each) that dominated R2's 12.4ms.
//  - k_init:  zero state, R0, DtD, ctab, yprev, scalars, barrier counters.
//  - k_setup: xxt -> 12 normalized squarings (+10 for DtD chain) -> power
//             matvecs -> fp64 matrix-free Rayleigh -> tau/thr. 19 barriers.
//  - k_loop:  200 x { phaseA(G+prox+conv) [bar] done-check phaseB(Ax,R,
//             hankel partials) [bar] } + final out copy. Early exit = uniform
//             break on device-set done flag (reference-equivalent).
// Co-residency: 256 blocks x 512 thr, __launch_bounds__(512,2), ~19KB LDS ->
// 1+ block/CU guaranteed on the 256-CU MI355X; barrier is deadlock-free.
// ---------------------------------------------------------------------------

#define L 128
#define D 512
#define M 2048
#define TAIL (L - 1)     // 127
#define MAXIT 200
#define EPSV 1e-5f
#define LAM1 0.1f
#define LAM2C 0.1f
#define LD (L * D)       // 65536
#define NBLK 256
#define NTHR 512

// workspace offsets (floats)
#define OFF_A     0           // 2 x LD
#define OFF_BM    131072      // 2 x LD
#define OFF_R     262144      // L*M
#define OFF_AX    524288      // L*M
#define OFF_P     786432      // 512x512 (setup)
#define OFF_Q     1048576     // 512x512 (setup)
#define OFF_DTD   1310720     // 128x128
#define OFF_DP    1327104     // 128x128
#define OFF_DQ    1343488     // 128x128
#define OFF_CTAB  1359872     // 256
#define OFF_YPREV 1360128     // 128
#define OFF_PART  1360256     // 16 x 128
#define OFF_WV    1362304     // 512
#define OFF_VV    1362816     // 512
#define OFF_T64   1363328     // 2048 doubles
#define OFF_Y64   1367424     // 512 doubles
#define OFF_SCAL  1368448     // 64

#define SC_MX    0    // x-chain squaring maxima 0..12
#define SC_MXD   24   // delta-chain maxima 24..34
#define SC_EIGD  44
#define SC_TAU   45
#define SC_THR   46
#define SI_DONE  48
#define SI_CNT   52
#define SI_GEN   53

__device__ __forceinline__ float delta_elem(int i, int j) {
  if (i == 0) return 0.f;
  if (i == 1) return (j == 0) ? -1.f : (j == 1 ? 1.f : 0.f);
  return (j == i) ? 1.f : (j == i - 1 ? -2.f : (j == i - 2 ? 1.f : 0.f));
}

// ---- grid barrier: generation-based, device scope, deadlock-free at 1 blk/CU
__device__ __forceinline__ void gbar(float* ws) {
  __syncthreads();
  if (threadIdx.x == 0) {
    unsigned* cnt = (unsigned*)(ws + OFF_SCAL) + SI_CNT;
    unsigned* gen = (unsigned*)(ws + OFF_SCAL) + SI_GEN;
    __threadfence();  // release my block's stores (agent scope)
    unsigned g = __hip_atomic_load(gen, __ATOMIC_RELAXED, __HIP_MEMORY_SCOPE_AGENT);
    unsigned a = __hip_atomic_fetch_add(cnt, 1u, __ATOMIC_ACQ_REL, __HIP_MEMORY_SCOPE_AGENT);
    if (a == NBLK - 1) {
      __hip_atomic_store(cnt, 0u, __ATOMIC_RELAXED, __HIP_MEMORY_SCOPE_AGENT);
      __hip_atomic_store(gen, g + 1u, __ATOMIC_RELEASE, __HIP_MEMORY_SCOPE_AGENT);
    } else {
      while (__hip_atomic_load(gen, __ATOMIC_ACQUIRE, __HIP_MEMORY_SCOPE_AGENT) == g)
        __builtin_amdgcn_s_sleep(2);
    }
    __threadfence();  // acquire side: invalidate caches before next phase reads
  }
  __syncthreads();
}

// ---------------- init ------------------------------------------------------
__global__ __launch_bounds__(256) void k_init(float* __restrict__ ws,
                                              const float* __restrict__ part_y,
                                              const float* __restrict__ mask,
                                              const float* __restrict__ y0) {
  int gid = blockIdx.x * blockDim.x + threadIdx.x;
  int stride = gridDim.x * blockDim.x;
  for (int i = gid; i < 4 * LD; i += stride) ws[OFF_A + i] = 0.f;
  for (int i = gid; i < L * M; i += stride) ws[OFF_R + i] = -mask[i] * part_y[i];
  for (int i = gid; i < L * L; i += stride) {
    int r = i / L, c = i % L;
    float s = 0.f;
    for (int k = 0; k < L; ++k) s += delta_elem(k, r) * delta_elem(k, c);
    ws[OFF_DTD + i] = s;
  }
  if (gid < TAIL) ws[OFF_YPREV + gid] = y0[M + gid];
  if (gid == 0) {
    for (int i = 0; i < 64; ++i) ws[OFF_SCAL + i] = 0.f;  // incl done, cnt, gen
    ws[OFF_SCAL + SC_MXD] = 6.0f;  // exact max|DtD|
    float a = 1.f;
    for (int t = 0; t < MAXIT; ++t) {
      float an = (1.f + sqrtf(1.f + 4.f * a * a)) * 0.5f;
      ws[OFF_CTAB + t] = (a - 1.f) / an;
      a = an;
    }
  }
}

// ---- one 32x32-tile symmetric-GEMM step: dst = (src/m)^2, track max --------
template <int N, int TILES>
__device__ __forceinline__ void sq_step(const float* __restrict__ src,
                                        float* __restrict__ dst,
                                        float* __restrict__ scal,
                                        int si, int so, float* sm, int bt) {
  float sc = 1.0f / scal[si];
  int r0 = (bt / TILES) * 32, c0 = (bt % TILES) * 32;
  int rr = threadIdx.x >> 5, cl = threadIdx.x & 31;  // rr 0..15
  int c = c0 + cl;
  const float4* bc = (const float4*)(src + (size_t)c * N);
  const float4* a0p = (const float4*)(src + (size_t)(r0 + rr) * N);
  const float4* a1p = (const float4*)(src + (size_t)(r0 + rr + 16) * N);
  float a0 = 0.f, a1 = 0.f;
  for (int m4 = 0; m4 < N / 4; ++m4) {
    float4 b = bc[m4];
    float4 p = a0p[m4], q = a1p[m4];
    a0 += p.x * b.x + p.y * b.y + p.z * b.z + p.w * b.w;
    a1 += q.x * b.x + q.y * b.y + q.z * b.z + q.w * b.w;
  }
  a0 *= sc * sc; a1 *= sc * sc;
  dst[(size_t)(r0 + rr) * N + c] = a0;
  dst[(size_t)(r0 + rr + 16) * N + c] = a1;
  sm[threadIdx.x] = fmaxf(fabsf(a0), fabsf(a1));
  __syncthreads();
  for (int s = 256; s > 0; s >>= 1) {
    if ((int)threadIdx.x < s) sm[threadIdx.x] = fmaxf(sm[threadIdx.x], sm[threadIdx.x + s]);
    __syncthreads();
  }
  if (threadIdx.x == 0) atomicMax((int*)(scal + so), __float_as_int(sm[0]));
}

// ---------------- setup: spectral norms -> tau/thr (19 grid barriers) ------
__global__ __launch_bounds__(NTHR, 2) void k_setup(const float* __restrict__ x,
                                                   float* __restrict__ ws) {
  const int tid = threadIdx.x, bid = blockIdx.x;
  __shared__ float sm[NTHR];
  __shared__ double sdn[NTHR], sdd[NTHR];
  float* scal = ws + OFF_SCAL;

  // S1: P = x x^T (512x512), max -> SC_MX
  {
    int r0 = (bid >> 4) * 32, c0 = (bid & 15) * 32;
    int rr = tid >> 5, cl = tid & 31;
    int c = c0 + cl;
    const float4* xc = (const float4*)(x + (size_t)c * M);
    const float4* xr0 = (const float4*)(x + (size_t)(r0 + rr) * M);
    const float4* xr1 = (const float4*)(x + (size_t)(r0 + rr + 16) * M);
    float a0 = 0.f, a1 = 0.f;
    for (int m4 = 0; m4 < M / 4; ++m4) {
      float4 b = xc[m4];
      float4 p = xr0[m4], q = xr1[m4];
      a0 += p.x * b.x + p.y * b.y + p.z * b.z + p.w * b.w;
      a1 += q.x * b.x + q.y * b.y + q.z * b.z + q.w * b.w;
    }
    float* P = ws + OFF_P;
    P[(size_t)(r0 + rr) * D + c] = a0;
    P[(size_t)(r0 + rr + 16) * D + c] = a1;
    sm[tid] = fmaxf(fabsf(a0), fabsf(a1));
    __syncthreads();
    for (int s = 256; s > 0; s >>= 1) {
      if (tid < s) sm[tid] = fmaxf(sm[tid], sm[tid + s]);
      __syncthreads();
    }
    if (tid == 0) atomicMax((int*)(scal + SC_MX), __float_as_int(sm[0]));
  }
  gbar(ws);

  // S2: 12 x-chain squarings; delta-chain (10) folded into first steps on blocks<16
  for (int s = 0; s < 12; ++s) {
    if (bid < 16 && s < 10) {
      const float* src = (s == 0) ? ws + OFF_DTD : ((s & 1) ? ws + OFF_DP : ws + OFF_DQ);
      float* dst = (s & 1) ? ws + OFF_DQ : ws + OFF_DP;
      sq_step<128, 4>(src, dst, scal, SC_MXD + s, SC_MXD + s + 1, sm, bid);
    }
    __syncthreads();
    {
      const float* src = (s & 1) ? ws + OFF_Q : ws + OFF_P;
      float* dst = (s & 1) ? ws + OFF_P : ws + OFF_Q;
      sq_step<512, 16>(src, dst, scal, SC_MX + s, SC_MX + s + 1, sm, bid);
    }
    gbar(ws);
  }
  // x-chain final in P (s=11 odd -> dst P); delta final in dQ (s=9 odd -> dQ)

  const float* gP = ws + OFF_P;
  const float* dQ = ws + OFF_DQ;
  // S3a: WV = P*ones (b0); WD = dQ*ones (b1)
  if (bid == 0) {
    const float4* Pr = (const float4*)(gP + (size_t)tid * D);
    float a = 0.f;
    for (int j = 0; j < D / 4; ++j) { float4 v = Pr[j]; a += v.x + v.y + v.z + v.w; }
    ws[OFF_WV + tid] = a;
  }
  if (bid == 1 && tid < L) {
    const float4* Dr = (const float4*)(dQ + (size_t)tid * L);
    float a = 0.f;
    for (int j = 0; j < L / 4; ++j) { float4 v = Dr[j]; a += v.x + v.y + v.z + v.w; }
    ws[OFF_WV + 512 + tid] = a;  // WD stored after WV region? no: use OFF_WV+? 
  }
  gbar(ws);
  // NOTE: WD lives at OFF_VV+512.. wait — use dedicated slots below.
  // S3b: VV = P*WV (b0); WD2 = dQ*WD (b1)
  if (bid == 0) {
    const float4* Pr = (const float4*)(gP + (size_t)tid * D);
    const float4* v4 = (const float4*)(ws + OFF_WV);
    float a = 0.f;
    for (int j = 0; j < D / 4; ++j) {
      float4 p = Pr[j]; float4 v = v4[j];
      a += p.x * v.x + p.y * v.y + p.z * v.z + p.w * v.w;
    }
    ws[OFF_VV + tid] = a;
  }
  if (bid == 1 && tid < L) {
    const float* wd = ws + OFF_WV + 512;
    const float* Dr = dQ + (size_t)tid * L;
    float a = 0.f;
    for (int j = 0; j < L; ++j) a += Dr[j] * wd[j];
    ws[OFF_WV + 640 + tid] = a;  // WD2
  }
  gbar(ws);
  // S3c: WV = P*VV (b0); eigd Rayleigh on DtD with WD2 (b1)
  if (bid == 0) {
    const float4* Pr = (const float4*)(gP + (size_t)tid * D);
    const float4* v4 = (const float4*)(ws + OFF_VV);
    float a = 0.f;
    for (int j = 0; j < D / 4; ++j) {
      float4 p = Pr[j]; float4 v = v4[j];
      a += p.x * v.x + p.y * v.y + p.z * v.z + p.w * v.w;
    }
    ws[OFF_WV + tid] = a;
  }
  if (bid == 1) {
    float accv = 0.f, vv = 0.f;
    if (tid < L) {
      const float* v = ws + OFF_WV + 640;
      const float* DtD = ws + OFF_DTD;
      for (int j = 0; j < L; ++j) accv += DtD[(size_t)tid * L + j] * v[j];
      vv = v[tid];
    }
    sm[tid] = (tid < L) ? accv * vv : 0.f;
    sm[256 + (tid & 255)] = 0.f;
    __syncthreads();
    if (tid < L) sm[256 + tid] = vv * vv;
    __syncthreads();
    if (tid == 0) {
      float n = 0.f, d = 0.f;
      for (int k = 0; k < L; ++k) { n += sm[k]; d += sm[256 + k]; }
      scal[SC_EIGD] = n / d;
    }
  }
  gbar(ws);
  // S3d: VV = P*WV (b0)
  if (bid == 0) {
    const float4* Pr = (const float4*)(gP + (size_t)tid * D);
    const float4* v4 = (const float4*)(ws + OFF_WV);
    float a = 0.f;
    for (int j = 0; j < D / 4; ++j) {
      float4 p = Pr[j]; float4 v = v4[j];
      a += p.x * v.x + p.y * v.y + p.z * v.z + p.w * v.w;
    }
    ws[OFF_VV + tid] = a;
  }
  gbar(ws);
  // S4: T64 = x^T * VV  (fp64, blocks 0-3, coalesced across m)
  if (bid < 4) {
    int m = bid * NTHR + tid;
    double acc = 0.0;
    for (int i = 0; i < D; ++i) acc += (double)x[(size_t)i * M + m] * (double)ws[OFF_VV + i];
    ((double*)(ws + OFF_T64))[m] = acc;
  }
  gbar(ws);
  // S5: Y64 = x * T64 (fp64, block 0)
  if (bid == 0) {
    const double* t64 = (const double*)(ws + OFF_T64);
    double acc = 0.0;
    for (int m = 0; m < M; ++m) acc += (double)x[(size_t)tid * M + m] * t64[m];
    ((double*)(ws + OFF_Y64))[tid] = acc;
  }
  gbar(ws);
  // S6: tau, thr (block 0)
  if (bid == 0) {
    const double* y = (const double*)(ws + OFF_Y64);
    double vi = (double)ws[OFF_VV + tid];
    sdn[tid] = vi * y[tid];
    sdd[tid] = vi * vi;
    __syncthreads();
    for (int s = 256; s > 0; s >>= 1) {
      if (tid < s) { sdn[tid] += sdn[tid + s]; sdd[tid] += sdd[tid + s]; }
      __syncthreads();
    }
    if (tid == 0) {
      float max_sx = (float)(sdn[0] / sdd[0]);
      float eigD = scal[SC_EIGD];
      float tau = 1.0f / (2.0f * (max_sx + LAM1 * eigD));
      float lam2 = (tau * LAM2C > 0.1f) ? 0.1f / tau : LAM2C;
      scal[SC_TAU] = tau;
      scal[SC_THR] = tau * lam2;
    }
  }
}

// ---------------- main loop: 200 iterations, 2 barriers each ---------------
__global__ __launch_bounds__(NTHR, 2) void k_loop(const float* __restrict__ x,
                                                  const float* __restrict__ py,
                                                  const float* __restrict__ mask,
                                                  float* __restrict__ ws,
                                                  float* __restrict__ out) {
  __shared__ float g2buf[256];
  __shared__ float tile[16][65];
  __shared__ float snum[128], sden[128];
  __shared__ int flag;
  const int tid = threadIdx.x, bid = blockIdx.x;
  int* iscal = (int*)(ws + OFF_SCAL);
  const float tau = ws[OFF_SCAL + SC_TAU];
  const float thr = ws[OFF_SCAL + SC_THR];
  int par = 0;

  for (int t = 0; t < MAXIT; ++t) {
    // ---- phase A: conv check (block 0) + G = R@x^T + L1*DtD@A, prox ----
    if (bid == 0 && t >= 1) {
      if (tid < TAIL) {
        float s = 0.f;
#pragma unroll
        for (int slot = 0; slot < 16; ++slot) s += ws[OFF_PART + slot * 128 + tid];
        float ax = s / (float)(TAIL - tid);
        float yp = ws[OFF_YPREV + tid];
        float d0 = yp - ax;
        snum[tid] = d0 * d0;
        sden[tid] = yp * yp;
        ws[OFF_YPREV + tid] = ax;
      }
      __syncthreads();
      if (tid == 0) {
        float num = 0.f, den = 0.f;
        for (int k = 0; k < TAIL; ++k) { num += snum[k]; den += sden[k]; }
        float conv = sqrtf(num) / sqrtf(den);
        if (conv <= EPSV) iscal[SI_DONE] = 1;
      }
      __syncthreads();
    }
    {
      int rt = bid >> 4, ct = bid & 15;
      int oi = tid & 255;
      int r = rt * 8 + (oi >> 5);
      int c = ct * 32 + (oi & 31);
      int half = tid >> 8;
      const float4* Rp = (const float4*)(ws + OFF_R + (size_t)r * M) + half * 256;
      const float4* Xp = (const float4*)(x + (size_t)c * M) + half * 256;
      float a0 = 0.f, a1 = 0.f;
#pragma unroll 4
      for (int i = 0; i < 256; i += 2) {
        float4 ra = Rp[i], xa = Xp[i];
        float4 rb = Rp[i + 1], xb = Xp[i + 1];
        a0 += ra.x * xa.x + ra.y * xa.y + ra.z * xa.z + ra.w * xa.w;
        a1 += rb.x * xb.x + rb.y * xb.y + rb.z * xb.z + rb.w * xb.w;
      }
      float g2 = a0 + a1;
      if (half) g2buf[oi] = g2;
      __syncthreads();
      if (!half) {
        const float* Ao = ws + OFF_A + (size_t)(t & 1) * LD;
        const float4* Dr = (const float4*)(ws + OFF_DTD + (size_t)r * L);
        float gd = 0.f;
#pragma unroll 4
        for (int p4 = 0; p4 < 32; ++p4) {
          float4 dv = Dr[p4];
          gd += dv.x * Ao[(size_t)(p4 * 4 + 0) * D + c] + dv.y * Ao[(size_t)(p4 * 4 + 1) * D + c] +
                dv.z * Ao[(size_t)(p4 * 4 + 2) * D + c] + dv.w * Ao[(size_t)(p4 * 4 + 3) * D + c];
        }
        float g = g2 + g2buf[oi] + LAM1 * gd;
        float ctv = ws[OFF_CTAB + t];
        size_t off = (size_t)r * D + c;
        float aold = Ao[off];
        float bm = ws[OFF_BM + (size_t)(t & 1) * LD + off];
        float z = bm - tau * g;
        float az = fabsf(z) - thr;
        float anew = az > 0.f ? copysignf(az, z) : 0.f;
        ws[OFF_A + (size_t)((t + 1) & 1) * LD + off] = anew;
        ws[OFF_BM + (size_t)((t + 1) & 1) * LD + off] = aold + ctv * (anew - aold);
      }
    }
    gbar(ws);
    // ---- uniform early-exit check ----
    if (tid == 0) flag = __hip_atomic_load(iscal + SI_DONE, __ATOMIC_RELAXED, __HIP_MEMORY_SCOPE_AGENT);
    __syncthreads();
    if (flag) { par = t & 1; break; }
    // ---- phase B: Ax = A_new@x, R, hankel-tail partials ----
    {
      int rt = bid >> 5, ct = bid & 31;
      int half = tid >> 8, w2 = (tid >> 6) & 3, lane = tid & 63;
      int r0 = rt * 16 + w2 * 4;
      int c = ct * 64 + lane;
      const float* A = ws + OFF_A + (size_t)((t + 1) & 1) * LD;
      float acc0 = 0.f, acc1 = 0.f, acc2 = 0.f, acc3 = 0.f;
      int d4lo = half * 64;
#pragma unroll 2
      for (int d4 = d4lo; d4 < d4lo + 64; ++d4) {
        float xs0 = x[(size_t)(d4 * 4 + 0) * M + c];
        float xs1 = x[(size_t)(d4 * 4 + 1) * M + c];
        float xs2 = x[(size_t)(d4 * 4 + 2) * M + c];
        float xs3 = x[(size_t)(d4 * 4 + 3) * M + c];
        float4 a0v = ((const float4*)(A + (size_t)(r0 + 0) * D))[d4];
        float4 a1v = ((const float4*)(A + (size_t)(r0 + 1) * D))[d4];
        float4 a2v = ((const float4*)(A + (size_t)(r0 + 2) * D))[d4];
        float4 a3v = ((const float4*)(A + (size_t)(r0 + 3) * D))[d4];
        acc0 += a0v.x * xs0 + a0v.y * xs1 + a0v.z * xs2 + a0v.w * xs3;
        acc1 += a1v.x * xs0 + a1v.y * xs1 + a1v.z * xs2 + a1v.w * xs3;
        acc2 += a2v.x * xs0 + a2v.y * xs1 + a2v.z * xs2 + a2v.w * xs3;
        acc3 += a3v.x * xs0 + a3v.y * xs1 + a3v.z * xs2 + a3v.w * xs3;
      }
      if (half == 0) {
        tile[w2 * 4 + 0][lane] = acc0;
        tile[w2 * 4 + 1][lane] = acc1;
        tile[w2 * 4 + 2][lane] = acc2;
        tile[w2 * 4 + 3][lane] = acc3;
      }
      __syncthreads();
      if (half == 1) {
        float s0 = tile[w2 * 4 + 0][lane] + acc0;
        float s1 = tile[w2 * 4 + 1][lane] + acc1;
        float s2 = tile[w2 * 4 + 2][lane] + acc2;
        float s3 = tile[w2 * 4 + 3][lane] + acc3;
        size_t o0 = (size_t)(r0 + 0) * M + c;
        size_t o1 = (size_t)(r0 + 1) * M + c;
        size_t o2 = (size_t)(r0 + 2) * M + c;
        size_t o3 = (size_t)(r0 + 3) * M + c;
        ws[OFF_AX + o0] = s0; ws[OFF_R + o0] = mask[o0] * (s0 - py[o0]);
        ws[OFF_AX + o1] = s1; ws[OFF_R + o1] = mask[o1] * (s1 - py[o1]);
        ws[OFF_AX + o2] = s2; ws[OFF_R + o2] = mask[o2] * (s2 - py[o2]);
        ws[OFF_AX + o3] = s3; ws[OFF_R + o3] = mask[o3] * (s3 - py[o3]);
        tile[w2 * 4 + 0][lane] = s0;
        tile[w2 * 4 + 1][lane] = s1;
        tile[w2 * 4 + 2][lane] = s2;
        tile[w2 * 4 + 3][lane] = s3;
      }
      if (ct >= 30) {
        __syncthreads();
        int slot = rt * 2 + (ct - 30);
        if (tid < TAIL) {
          int kk = M + tid;
          int rbase = rt * 16, c0 = ct * 64;
          int rlo = max(rbase, kk - (c0 + 63));
          int rhi = min(rbase + 15, kk - c0);
          float s = 0.f;
          for (int r = rlo; r <= rhi; ++r) s += tile[r - rbase][(kk - r) - c0];
          ws[OFF_PART + slot * 128 + tid] = s;
        }
      }
    }
    gbar(ws);
  }

  // ---- final output copy ----
  {
    int gid = bid * NTHR + tid;
    for (int i = gid; i < L * M; i += NBLK * NTHR) out[i] = ws[OFF_AX + i];
    for (int i = gid; i < LD; i += NBLK * NTHR) out[L * M + i] = ws[OFF_A + (size_t)par * LD + i];
  }
}

// ---------------------------------------------------------------------------
extern "C" void kernel_launch(void* const* d_in, const int* in_sizes, int n_in,
                              void* d_out, int out_size, void* d_ws, size_t ws_size,
                              hipStream_t stream) {
  (void)in_sizes; (void)n_in; (void)out_size; (void)ws_size;
  const float* x = (const float*)d_in[0];
  const float* py = (const float*)d_in[1];
  const float* mk = (const float*)d_in[2];
  const float* y0 = (const float*)d_in[3];
  float* out = (float*)d_out;
  float* ws = (float*)d_ws;

  k_init<<<256, 256, 0, stream>>>(ws, py, mk, y0);
  k_setup<<<NBLK, NTHR, 0, stream>>>(x, ws);
  k_loop<<<NBLK, NTHR, 0, stream>>>(x, py, mk, ws, out);
}

// Round 4
// 24417.699 us; speedup vs baseline: 1.5362x; 1.5362x over previous
//
#include <hip/hip_runtime.h>
#include <math.h>

// ---------------------------------------------------------------------------
// FISTA sparse solver, L=128, D=512, M=2048, MAX_ITER=200, EPS=1e-5.
// R4 = R3 (persistent kernels, 3 launches) with the grid barrier fixed:
//  - R3 bug: ACQUIRE atomic spin load -> buffer_inv per poll -> L2 thrash
//    (VALUBusy 7.6%, 1.4GB HBM traffic, 35-75ms k_loop).
//  - R4: relaxed-only polls + s_sleep backoff; ONE __threadfence release
//    before arrival, ONE acquire after wake. Two-level arrival tree
//    (32 groups x 8) on padded cachelines; monotonic epochs (no resets);
//    separate counter sets for k_setup / k_loop.
// Phase bodies, conv check, done-flag semantics: verbatim from R3 (passed).
// ---------------------------------------------------------------------------

#define L 128
#define D 512
#define M 2048
#define TAIL (L - 1)     // 127
#define MAXIT 200
#define EPSV 1e-5f
#define LAM1 0.1f
#define LAM2C 0.1f
#define LD (L * D)       // 65536
#define NBLK 256
#define NTHR 512

// workspace offsets (floats)
#define OFF_A     0           // 2 x LD
#define OFF_BM    131072      // 2 x LD
#define OFF_R     262144      // L*M
#define OFF_AX    524288      // L*M
#define OFF_P     786432      // 512x512 (setup)
#define OFF_Q     1048576     // 512x512 (setup)
#define OFF_DTD   1310720     // 128x128
#define OFF_DP    1327104     // 128x128
#define OFF_DQ    1343488     // 128x128
#define OFF_CTAB  1359872     // 256
#define OFF_YPREV 1360128     // 128
#define OFF_PART  1360256     // 16 x 128
#define OFF_WV    1362304     // 512 (+WD at +512, WD2 at +640)
#define OFF_VV    1362816     // 512
#define OFF_T64   1363328     // 2048 doubles
#define OFF_Y64   1367424     // 512 doubles
#define OFF_SCAL  1368448     // 64
// barrier counters (ints), monotonic epochs, two independent sets
#define OFF_GRPA  1368512     // 32 groups x 16 ints
#define OFF_ROOTA 1369024     // cnt@+0, gen@+16 (32 ints)
#define OFF_GRPB  1369056     // 32 groups x 16 ints
#define OFF_ROOTB 1369568     // cnt@+0, gen@+16 (32 ints) -> end 1369600

#define SC_MX    0    // x-chain squaring maxima 0..12
#define SC_MXD   24   // delta-chain maxima 24..34
#define SC_EIGD  44
#define SC_TAU   45
#define SC_THR   46
#define SI_DONE  48

__device__ __forceinline__ float delta_elem(int i, int j) {
  if (i == 0) return 0.f;
  if (i == 1) return (j == 0) ? -1.f : (j == 1 ? 1.f : 0.f);
  return (j == i) ? 1.f : (j == i - 1 ? -2.f : (j == i - 2 ? 1.f : 0.f));
}

// ---- grid barrier: relaxed tree arrival + relaxed spin; fences once each ---
// grp/root counters are MONOTONIC: epoch ep expects grp to reach 8*(ep+1) and
// root 32*(ep+1); gen is stored as ep+1 by the last arriver. Epochs must be
// consecutive among *called* barriers (breaks skip all later epochs: ok).
__device__ __forceinline__ void gbar(float* ws, int grpOff, int rootOff, unsigned ep) {
  __syncthreads();
  if (threadIdx.x == 0) {
    unsigned* grp = (unsigned*)(ws + grpOff);
    unsigned* root = (unsigned*)(ws + rootOff);
    unsigned* gen = root + 16;
    __threadfence();  // release: writeback my XCD's dirty lines (ONCE)
    unsigned g = (unsigned)blockIdx.x >> 3;  // 32 groups of 8
    unsigned a = __hip_atomic_fetch_add(&grp[g * 16], 1u, __ATOMIC_RELAXED,
                                        __HIP_MEMORY_SCOPE_AGENT);
    if (a == ep * 8u + 7u) {  // last of my group this epoch
      unsigned r = __hip_atomic_fetch_add(root, 1u, __ATOMIC_RELAXED,
                                          __HIP_MEMORY_SCOPE_AGENT);
      if (r == ep * 32u + 31u)
        __hip_atomic_store(gen, ep + 1u, __ATOMIC_RELAXED, __HIP_MEMORY_SCOPE_AGENT);
    }
    while (__hip_atomic_load(gen, __ATOMIC_RELAXED, __HIP_MEMORY_SCOPE_AGENT) <= ep)
      __builtin_amdgcn_s_sleep(8);
    __threadfence();  // acquire: invalidate stale lines (ONCE)
  }
  __syncthreads();
}

// ---------------- init ------------------------------------------------------
__global__ __launch_bounds__(256) void k_init(float* __restrict__ ws,
                                              const float* __restrict__ part_y,
                                              const float* __restrict__ mask,
                                              const float* __restrict__ y0) {
  int gid = blockIdx.x * blockDim.x + threadIdx.x;
  int stride = gridDim.x * blockDim.x;
  for (int i = gid; i < 4 * LD; i += stride) ws[OFF_A + i] = 0.f;
  for (int i = gid; i < L * M; i += stride) ws[OFF_R + i] = -mask[i] * part_y[i];
  for (int i = gid; i < L * L; i += stride) {
    int r = i / L, c = i % L;
    float s = 0.f;
    for (int k = 0; k < L; ++k) s += delta_elem(k, r) * delta_elem(k, c);
    ws[OFF_DTD + i] = s;
  }
  for (int i = gid; i < 1088; i += stride) ((unsigned*)(ws + OFF_GRPA))[i] = 0u;
  if (gid < TAIL) ws[OFF_YPREV + gid] = y0[M + gid];
  if (gid == 0) {
    for (int i = 0; i < 64; ++i) ws[OFF_SCAL + i] = 0.f;  // incl done flag
    ws[OFF_SCAL + SC_MXD] = 6.0f;  // exact max|DtD|
    float a = 1.f;
    for (int t = 0; t < MAXIT; ++t) {
      float an = (1.f + sqrtf(1.f + 4.f * a * a)) * 0.5f;
      ws[OFF_CTAB + t] = (a - 1.f) / an;
      a = an;
    }
  }
}

// ---- one 32x32-tile symmetric-GEMM step: dst = (src/m)^2, track max --------
template <int N, int TILES>
__device__ __forceinline__ void sq_step(const float* __restrict__ src,
                                        float* __restrict__ dst,
                                        float* __restrict__ scal,
                                        int si, int so, float* sm, int bt) {
  float sc = 1.0f / scal[si];
  int r0 = (bt / TILES) * 32, c0 = (bt % TILES) * 32;
  int rr = threadIdx.x >> 5, cl = threadIdx.x & 31;  // rr 0..15
  int c = c0 + cl;
  const float4* bc = (const float4*)(src + (size_t)c * N);
  const float4* a0p = (const float4*)(src + (size_t)(r0 + rr) * N);
  const float4* a1p = (const float4*)(src + (size_t)(r0 + rr + 16) * N);
  float a0 = 0.f, a1 = 0.f;
  for (int m4 = 0; m4 < N / 4; ++m4) {
    float4 b = bc[m4];
    float4 p = a0p[m4], q = a1p[m4];
    a0 += p.x * b.x + p.y * b.y + p.z * b.z + p.w * b.w;
    a1 += q.x * b.x + q.y * b.y + q.z * b.z + q.w * b.w;
  }
  a0 *= sc * sc; a1 *= sc * sc;
  dst[(size_t)(r0 + rr) * N + c] = a0;
  dst[(size_t)(r0 + rr + 16) * N + c] = a1;
  sm[threadIdx.x] = fmaxf(fabsf(a0), fabsf(a1));
  __syncthreads();
  for (int s = 256; s > 0; s >>= 1) {
    if ((int)threadIdx.x < s) sm[threadIdx.x] = fmaxf(sm[threadIdx.x], sm[threadIdx.x + s]);
    __syncthreads();
  }
  if (threadIdx.x == 0) atomicMax((int*)(scal + so), __float_as_int(sm[0]));
}

// ---------------- setup: spectral norms -> tau/thr (19 barriers, set A) ----
__global__ __launch_bounds__(NTHR, 2) void k_setup(const float* __restrict__ x,
                                                   float* __restrict__ ws) {
  const int tid = threadIdx.x, bid = blockIdx.x;
  __shared__ float sm[NTHR];
  __shared__ double sdn[NTHR], sdd[NTHR];
  float* scal = ws + OFF_SCAL;
  unsigned ep = 0;

  // S1: P = x x^T (512x512), max -> SC_MX
  {
    int r0 = (bid >> 4) * 32, c0 = (bid & 15) * 32;
    int rr = tid >> 5, cl = tid & 31;
    int c = c0 + cl;
    const float4* xc = (const float4*)(x + (size_t)c * M);
    const float4* xr0 = (const float4*)(x + (size_t)(r0 + rr) * M);
    const float4* xr1 = (const float4*)(x + (size_t)(r0 + rr + 16) * M);
    float a0 = 0.f, a1 = 0.f;
    for (int m4 = 0; m4 < M / 4; ++m4) {
      float4 b = xc[m4];
      float4 p = xr0[m4], q = xr1[m4];
      a0 += p.x * b.x + p.y * b.y + p.z * b.z + p.w * b.w;
      a1 += q.x * b.x + q.y * b.y + q.z * b.z + q.w * b.w;
    }
    float* P = ws + OFF_P;
    P[(size_t)(r0 + rr) * D + c] = a0;
    P[(size_t)(r0 + rr + 16) * D + c] = a1;
    sm[tid] = fmaxf(fabsf(a0), fabsf(a1));
    __syncthreads();
    for (int s = 256; s > 0; s >>= 1) {
      if (tid < s) sm[tid] = fmaxf(sm[tid], sm[tid + s]);
      __syncthreads();
    }
    if (tid == 0) atomicMax((int*)(scal + SC_MX), __float_as_int(sm[0]));
  }
  gbar(ws, OFF_GRPA, OFF_ROOTA, ep++);

  // S2: 12 x-chain squarings; delta-chain (10) folded on blocks<16
  for (int s = 0; s < 12; ++s) {
    if (bid < 16 && s < 10) {
      const float* src = (s == 0) ? ws + OFF_DTD : ((s & 1) ? ws + OFF_DP : ws + OFF_DQ);
      float* dst = (s & 1) ? ws + OFF_DQ : ws + OFF_DP;
      sq_step<128, 4>(src, dst, scal, SC_MXD + s, SC_MXD + s + 1, sm, bid);
    }
    __syncthreads();
    {
      const float* src = (s & 1) ? ws + OFF_Q : ws + OFF_P;
      float* dst = (s & 1) ? ws + OFF_P : ws + OFF_Q;
      sq_step<512, 16>(src, dst, scal, SC_MX + s, SC_MX + s + 1, sm, bid);
    }
    gbar(ws, OFF_GRPA, OFF_ROOTA, ep++);
  }
  // x-chain final in P; delta final in dQ

  const float* gP = ws + OFF_P;
  const float* dQ = ws + OFF_DQ;
  // S3a: WV = P*ones (b0); WD = dQ*ones (b1)
  if (bid == 0) {
    const float4* Pr = (const float4*)(gP + (size_t)tid * D);
    float a = 0.f;
    for (int j = 0; j < D / 4; ++j) { float4 v = Pr[j]; a += v.x + v.y + v.z + v.w; }
    ws[OFF_WV + tid] = a;
  }
  if (bid == 1 && tid < L) {
    const float4* Dr = (const float4*)(dQ + (size_t)tid * L);
    float a = 0.f;
    for (int j = 0; j < L / 4; ++j) { float4 v = Dr[j]; a += v.x + v.y + v.z + v.w; }
    ws[OFF_WV + 512 + tid] = a;  // WD
  }
  gbar(ws, OFF_GRPA, OFF_ROOTA, ep++);
  // S3b: VV = P*WV (b0); WD2 = dQ*WD (b1)
  if (bid == 0) {
    const float4* Pr = (const float4*)(gP + (size_t)tid * D);
    const float4* v4 = (const float4*)(ws + OFF_WV);
    float a = 0.f;
    for (int j = 0; j < D / 4; ++j) {
      float4 p = Pr[j]; float4 v = v4[j];
      a += p.x * v.x + p.y * v.y + p.z * v.z + p.w * v.w;
    }
    ws[OFF_VV + tid] = a;
  }
  if (bid == 1 && tid < L) {
    const float* wd = ws + OFF_WV + 512;
    const float* Dr = dQ + (size_t)tid * L;
    float a = 0.f;
    for (int j = 0; j < L; ++j) a += Dr[j] * wd[j];
    ws[OFF_WV + 640 + tid] = a;  // WD2
  }
  gbar(ws, OFF_GRPA, OFF_ROOTA, ep++);
  // S3c: WV = P*VV (b0); eigd Rayleigh on DtD with WD2 (b1)
  if (bid == 0) {
    const float4* Pr = (const float4*)(gP + (size_t)tid * D);
    const float4* v4 = (const float4*)(ws + OFF_VV);
    float a = 0.f;
    for (int j = 0; j < D / 4; ++j) {
      float4 p = Pr[j]; float4 v = v4[j];
      a += p.x * v.x + p.y * v.y + p.z * v.z + p.w * v.w;
    }
    ws[OFF_WV + tid] = a;
  }
  if (bid == 1) {
    float accv = 0.f, vv = 0.f;
    if (tid < L) {
      const float* v = ws + OFF_WV + 640;
      const float* DtD = ws + OFF_DTD;
      for (int j = 0; j < L; ++j) accv += DtD[(size_t)tid * L + j] * v[j];
      vv = v[tid];
    }
    sm[tid] = (tid < L) ? accv * vv : 0.f;
    sm[256 + (tid & 255)] = 0.f;
    __syncthreads();
    if (tid < L) sm[256 + tid] = vv * vv;
    __syncthreads();
    if (tid == 0) {
      float n = 0.f, d = 0.f;
      for (int k = 0; k < L; ++k) { n += sm[k]; d += sm[256 + k]; }
      scal[SC_EIGD] = n / d;
    }
  }
  gbar(ws, OFF_GRPA, OFF_ROOTA, ep++);
  // S3d: VV = P*WV (b0)
  if (bid == 0) {
    const float4* Pr = (const float4*)(gP + (size_t)tid * D);
    const float4* v4 = (const float4*)(ws + OFF_WV);
    float a = 0.f;
    for (int j = 0; j < D / 4; ++j) {
      float4 p = Pr[j]; float4 v = v4[j];
      a += p.x * v.x + p.y * v.y + p.z * v.z + p.w * v.w;
    }
    ws[OFF_VV + tid] = a;
  }
  gbar(ws, OFF_GRPA, OFF_ROOTA, ep++);
  // S4: T64 = x^T * VV (fp64, blocks 0-3)
  if (bid < 4) {
    int m = bid * NTHR + tid;
    double acc = 0.0;
    for (int i = 0; i < D; ++i) acc += (double)x[(size_t)i * M + m] * (double)ws[OFF_VV + i];
    ((double*)(ws + OFF_T64))[m] = acc;
  }
  gbar(ws, OFF_GRPA, OFF_ROOTA, ep++);
  // S5: Y64 = x * T64 (fp64, block 0)
  if (bid == 0) {
    const double* t64 = (const double*)(ws + OFF_T64);
    double acc = 0.0;
    for (int m = 0; m < M; ++m) acc += (double)x[(size_t)tid * M + m] * t64[m];
    ((double*)(ws + OFF_Y64))[tid] = acc;
  }
  gbar(ws, OFF_GRPA, OFF_ROOTA, ep++);
  // S6: tau, thr (block 0)
  if (bid == 0) {
    const double* y = (const double*)(ws + OFF_Y64);
    double vi = (double)ws[OFF_VV + tid];
    sdn[tid] = vi * y[tid];
    sdd[tid] = vi * vi;
    __syncthreads();
    for (int s = 256; s > 0; s >>= 1) {
      if (tid < s) { sdn[tid] += sdn[tid + s]; sdd[tid] += sdd[tid + s]; }
      __syncthreads();
    }
    if (tid == 0) {
      float max_sx = (float)(sdn[0] / sdd[0]);
      float eigD = scal[SC_EIGD];
      float tau = 1.0f / (2.0f * (max_sx + LAM1 * eigD));
      float lam2 = (tau * LAM2C > 0.1f) ? 0.1f / tau : LAM2C;
      scal[SC_TAU] = tau;
      scal[SC_THR] = tau * lam2;
    }
  }
}

// ---------------- main loop: 200 iterations, 2 barriers each (set B) -------
__global__ __launch_bounds__(NTHR, 2) void k_loop(const float* __restrict__ x,
                                                  const float* __restrict__ py,
                                                  const float* __restrict__ mask,
                                                  float* __restrict__ ws,
                                                  float* __restrict__ out) {
  __shared__ float g2buf[256];
  __shared__ float tile[16][65];
  __shared__ float snum[128], sden[128];
  __shared__ int flag;
  const int tid = threadIdx.x, bid = blockIdx.x;
  int* iscal = (int*)(ws + OFF_SCAL);
  const float tau = ws[OFF_SCAL + SC_TAU];
  const float thr = ws[OFF_SCAL + SC_THR];
  int par = 0;

  for (int t = 0; t < MAXIT; ++t) {
    // ---- phase A: conv check (block 0) + G = R@x^T + L1*DtD@A, prox ----
    if (bid == 0 && t >= 1) {
      if (tid < TAIL) {
        float s = 0.f;
#pragma unroll
        for (int slot = 0; slot < 16; ++slot) s += ws[OFF_PART + slot * 128 + tid];
        float ax = s / (float)(TAIL - tid);
        float yp = ws[OFF_YPREV + tid];
        float d0 = yp - ax;
        snum[tid] = d0 * d0;
        sden[tid] = yp * yp;
        ws[OFF_YPREV + tid] = ax;
      }
      __syncthreads();
      if (tid == 0) {
        float num = 0.f, den = 0.f;
        for (int k = 0; k < TAIL; ++k) { num += snum[k]; den += sden[k]; }
        float conv = sqrtf(num) / sqrtf(den);
        if (conv <= EPSV) iscal[SI_DONE] = 1;
      }
      __syncthreads();
    }
    {
      int rt = bid >> 4, ct = bid & 15;
      int oi = tid & 255;
      int r = rt * 8 + (oi >> 5);
      int c = ct * 32 + (oi & 31);
      int half = tid >> 8;
      const float4* Rp = (const float4*)(ws + OFF_R + (size_t)r * M) + half * 256;
      const float4* Xp = (const float4*)(x + (size_t)c * M) + half * 256;
      float a0 = 0.f, a1 = 0.f;
#pragma unroll 4
      for (int i = 0; i < 256; i += 2) {
        float4 ra = Rp[i], xa = Xp[i];
        float4 rb = Rp[i + 1], xb = Xp[i + 1];
        a0 += ra.x * xa.x + ra.y * xa.y + ra.z * xa.z + ra.w * xa.w;
        a1 += rb.x * xb.x + rb.y * xb.y + rb.z * xb.z + rb.w * xb.w;
      }
      float g2 = a0 + a1;
      if (half) g2buf[oi] = g2;
      __syncthreads();
      if (!half) {
        const float* Ao = ws + OFF_A + (size_t)(t & 1) * LD;
        const float4* Dr = (const float4*)(ws + OFF_DTD + (size_t)r * L);
        float gd = 0.f;
#pragma unroll 4
        for (int p4 = 0; p4 < 32; ++p4) {
          float4 dv = Dr[p4];
          gd += dv.x * Ao[(size_t)(p4 * 4 + 0) * D + c] + dv.y * Ao[(size_t)(p4 * 4 + 1) * D + c] +
                dv.z * Ao[(size_t)(p4 * 4 + 2) * D + c] + dv.w * Ao[(size_t)(p4 * 4 + 3) * D + c];
        }
        float g = g2 + g2buf[oi] + LAM1 * gd;
        float ctv = ws[OFF_CTAB + t];
        size_t off = (size_t)r * D + c;
        float aold = Ao[off];
        float bm = ws[OFF_BM + (size_t)(t & 1) * LD + off];
        float z = bm - tau * g;
        float az = fabsf(z) - thr;
        float anew = az > 0.f ? copysignf(az, z) : 0.f;
        ws[OFF_A + (size_t)((t + 1) & 1) * LD + off] = anew;
        ws[OFF_BM + (size_t)((t + 1) & 1) * LD + off] = aold + ctv * (anew - aold);
      }
    }
    gbar(ws, OFF_GRPB, OFF_ROOTB, 2u * t);
    // ---- uniform early-exit check ----
    if (tid == 0) flag = __hip_atomic_load(iscal + SI_DONE, __ATOMIC_RELAXED, __HIP_MEMORY_SCOPE_AGENT);
    __syncthreads();
    if (flag) { par = t & 1; break; }
    // ---- phase B: Ax = A_new@x, R, hankel-tail partials ----
    {
      int rt = bid >> 5, ct = bid & 31;
      int half = tid >> 8, w2 = (tid >> 6) & 3, lane = tid & 63;
      int r0 = rt * 16 + w2 * 4;
      int c = ct * 64 + lane;
      const float* A = ws + OFF_A + (size_t)((t + 1) & 1) * LD;
      float acc0 = 0.f, acc1 = 0.f, acc2 = 0.f, acc3 = 0.f;
      int d4lo = half * 64;
#pragma unroll 2
      for (int d4 = d4lo; d4 < d4lo + 64; ++d4) {
        float xs0 = x[(size_t)(d4 * 4 + 0) * M + c];
        float xs1 = x[(size_t)(d4 * 4 + 1) * M + c];
        float xs2 = x[(size_t)(d4 * 4 + 2) * M + c];
        float xs3 = x[(size_t)(d4 * 4 + 3) * M + c];
        float4 a0v = ((const float4*)(A + (size_t)(r0 + 0) * D))[d4];
        float4 a1v = ((const float4*)(A + (size_t)(r0 + 1) * D))[d4];
        float4 a2v = ((const float4*)(A + (size_t)(r0 + 2) * D))[d4];
        float4 a3v = ((const float4*)(A + (size_t)(r0 + 3) * D))[d4];
        acc0 += a0v.x * xs0 + a0v.y * xs1 + a0v.z * xs2 + a0v.w * xs3;
        acc1 += a1v.x * xs0 + a1v.y * xs1 + a1v.z * xs2 + a1v.w * xs3;
        acc2 += a2v.x * xs0 + a2v.y * xs1 + a2v.z * xs2 + a2v.w * xs3;
        acc3 += a3v.x * xs0 + a3v.y * xs1 + a3v.z * xs2 + a3v.w * xs3;
      }
      if (half == 0) {
        tile[w2 * 4 + 0][lane] = acc0;
        tile[w2 * 4 + 1][lane] = acc1;
        tile[w2 * 4 + 2][lane] = acc2;
        tile[w2 * 4 + 3][lane] = acc3;
      }
      __syncthreads();
      if (half == 1) {
        float s0 = tile[w2 * 4 + 0][lane] + acc0;
        float s1 = tile[w2 * 4 + 1][lane] + acc1;
        float s2 = tile[w2 * 4 + 2][lane] + acc2;
        float s3 = tile[w2 * 4 + 3][lane] + acc3;
        size_t o0 = (size_t)(r0 + 0) * M + c;
        size_t o1 = (size_t)(r0 + 1) * M + c;
        size_t o2 = (size_t)(r0 + 2) * M + c;
        size_t o3 = (size_t)(r0 + 3) * M + c;
        ws[OFF_AX + o0] = s0; ws[OFF_R + o0] = mask[o0] * (s0 - py[o0]);
        ws[OFF_AX + o1] = s1; ws[OFF_R + o1] = mask[o1] * (s1 - py[o1]);
        ws[OFF_AX + o2] = s2; ws[OFF_R + o2] = mask[o2] * (s2 - py[o2]);
        ws[OFF_AX + o3] = s3; ws[OFF_R + o3] = mask[o3] * (s3 - py[o3]);
        tile[w2 * 4 + 0][lane] = s0;
        tile[w2 * 4 + 1][lane] = s1;
        tile[w2 * 4 + 2][lane] = s2;
        tile[w2 * 4 + 3][lane] = s3;
      }
      if (ct >= 30) {
        __syncthreads();
        int slot = rt * 2 + (ct - 30);
        if (tid < TAIL) {
          int kk = M + tid;
          int rbase = rt * 16, c0 = ct * 64;
          int rlo = max(rbase, kk - (c0 + 63));
          int rhi = min(rbase + 15, kk - c0);
          float s = 0.f;
          for (int r = rlo; r <= rhi; ++r) s += tile[r - rbase][(kk - r) - c0];
          ws[OFF_PART + slot * 128 + tid] = s;
        }
      }
    }
    gbar(ws, OFF_GRPB, OFF_ROOTB, 2u * t + 1u);
  }

  // ---- final output copy ----
  {
    int gid = bid * NTHR + tid;
    for (int i = gid; i < L * M; i += NBLK * NTHR) out[i] = ws[OFF_AX + i];
    for (int i = gid; i < LD; i += NBLK * NTHR) out[L * M + i] = ws[OFF_A + (size_t)par * LD + i];
  }
}

// ---------------------------------------------------------------------------
extern "C" void kernel_launch(void* const* d_in, const int* in_sizes, int n_in,
                              void* d_out, int out_size, void* d_ws, size_t ws_size,
                              hipStream_t stream) {
  (void)in_sizes; (void)n_in; (void)out_size; (void)ws_size;
  const float* x = (const float*)d_in[0];
  const float* py = (const float*)d_in[1];
  const float* mk = (const float*)d_in[2];
  const float* y0 = (const float*)d_in[3];
  float* out = (float*)d_out;
  float* ws = (float*)d_ws;

  k_init<<<256, 256, 0, stream>>>(ws, py, mk, y0);
  k_setup<<<NBLK, NTHR, 0, stream>>>(x, ws);
  k_loop<<<NBLK, NTHR, 0, stream>>>(x, py, mk, ws, out);
}